// Round 22
// baseline (354.304 us; speedup 1.0000x reference)
//
#include <hip/hip_runtime.h>

#define NNODES 100000
#define NEDGES 1600000
#define IN_CH 128
#define HID 64
#define HEADS 4
#define OUT_CH 16
#define OUT_SIZE 4
#define NEG_SLOPE 0.2f
#define NXCD 8
#define CAP 64
#define CAP_SHIFT 6
#define UNR 8

typedef float f32x4 __attribute__((ext_vector_type(4)));

// ---------------- fused prep: slotted edge scatter ++ layer-0 GEMM ----------------
// 40-block groups = 32 slot-fill + 8 linear blocks (complementary pipes).
// Slot branch: ballot-compact matching (d,s) into LDS, then scatter with
// FULL lane density (was ~8/64 active lanes). LDS overlays the GEMM tiles.
__global__ __launch_bounds__(256, 4) void k_prep(
        const int* __restrict__ src, const int* __restrict__ dst,
        int* __restrict__ cursor, int* __restrict__ slots, int E, int rng, int nslot,
        const float* __restrict__ x, const float* __restrict__ W,
        const float* __restrict__ bias, const float* __restrict__ att,
        float* __restrict__ h, float* __restrict__ si, float* __restrict__ sj,
        int nlin, int n) {
    constexpr int BM = 64, BK = 64;
    constexpr int LDK = BK + 16;   // 80
    constexpr int LDB = HID + 4;   // 68
    __shared__ char smem[(BM * LDK + BK * LDB) * 4];   // 37888 B, overlaid
    __shared__ int lcnt;

    const int grp40 = blockIdx.x / 40;
    const int r40   = blockIdx.x % 40;

    if (r40 < 32) {
        // ---- slot-fill branch (compacted) ----
        const int slotId = grp40 * 32 + r40;
        if (slotId >= nslot) return;
        const int range = slotId & (NXCD - 1);   // == blockIdx.x & 7 (physical XCD)
        const int chunk = slotId >> 3;
        const int lo = range * rng, hi = lo + rng;
        const int base = chunk * 2048;
        int* lds_d = (int*)smem;          // up to 2048
        int* lds_s = lds_d + 2048;        // up to 2048
        if (threadIdx.x == 0) lcnt = 0;
        __syncthreads();
        const int lane = threadIdx.x & 63;
        #pragma unroll
        for (int i = 0; i < 8; ++i) {
            int e = base + i * 256 + threadIdx.x;
            int d = 0, s = 0;
            bool m = false;
            if (e < E) {
                d = dst[e];
                m = (d >= lo && d < hi);
            }
            unsigned long long mask = __ballot(m);
            if (m) s = src[e];
            int prefix = __popcll(mask & ((1ull << lane) - 1ull));
            int cw = __popcll(mask);
            int b0 = 0;
            if (lane == 0 && cw) b0 = atomicAdd(&lcnt, cw);
            b0 = __shfl(b0, 0);
            if (m) { lds_d[b0 + prefix] = d; lds_s[b0 + prefix] = s; }
        }
        __syncthreads();
        const int cnt = lcnt;
        for (int i = threadIdx.x; i < cnt; i += 256) {
            int d = lds_d[i];
            int pos = atomicAdd(&cursor[d], 1);
            if (pos < CAP) slots[((size_t)d << CAP_SHIFT) + pos] = lds_s[i];
        }
        return;
    }

    // ---- layer-0 linear branch ----
    const int linId = grp40 * 8 + (r40 - 32);
    if (linId >= nlin) return;

    constexpr int IN = IN_CH;
    float (*As)[LDK] = (float(*)[LDK])smem;
    float (*Bs)[LDB] = (float(*)[LDB])(smem + BM * LDK * 4);

    const int tid = threadIdx.x;
    const int node0 = linId * BM;
    const int g = tid >> 4;
    const int v = tid & 15;
    const int tn = v * 4;

    float acc[4][4] = {};
    float4 ra[4], rb[4];

    #pragma unroll
    for (int i = 0; i < 4; ++i) {
        int m = g + 16 * i;
        int gm = node0 + m;
        ra[i] = make_float4(0.f, 0.f, 0.f, 0.f);
        if (gm < n) ra[i] = *reinterpret_cast<const float4*>(&x[(size_t)gm * IN + tn]);
        rb[i] = *reinterpret_cast<const float4*>(&W[(size_t)m * IN + tn]);
    }

    #pragma unroll
    for (int kk = 0; kk < IN; kk += BK) {
        #pragma unroll
        for (int i = 0; i < 4; ++i) {
            int m = g + 16 * i;
            *reinterpret_cast<float4*>(&As[m][tn]) = ra[i];
            Bs[tn + 0][m] = rb[i].x; Bs[tn + 1][m] = rb[i].y;
            Bs[tn + 2][m] = rb[i].z; Bs[tn + 3][m] = rb[i].w;
        }
        __syncthreads();
        if (kk + BK < IN) {
            #pragma unroll
            for (int i = 0; i < 4; ++i) {
                int m = g + 16 * i;
                int gm = node0 + m;
                ra[i] = make_float4(0.f, 0.f, 0.f, 0.f);
                if (gm < n)
                    ra[i] = *reinterpret_cast<const float4*>(&x[(size_t)gm * IN + kk + BK + tn]);
                rb[i] = *reinterpret_cast<const float4*>(&W[(size_t)m * IN + kk + BK + tn]);
            }
        }
        #pragma unroll
        for (int k4 = 0; k4 < BK; k4 += 4) {
            float4 b0 = *reinterpret_cast<const float4*>(&Bs[k4 + 0][tn]);
            float4 b1 = *reinterpret_cast<const float4*>(&Bs[k4 + 1][tn]);
            float4 b2 = *reinterpret_cast<const float4*>(&Bs[k4 + 2][tn]);
            float4 b3 = *reinterpret_cast<const float4*>(&Bs[k4 + 3][tn]);
            #pragma unroll
            for (int r = 0; r < 4; ++r) {
                float4 a = *reinterpret_cast<const float4*>(&As[g + 16 * r][k4]);
                acc[r][0] = fmaf(a.x, b0.x, acc[r][0]);
                acc[r][1] = fmaf(a.x, b0.y, acc[r][1]);
                acc[r][2] = fmaf(a.x, b0.z, acc[r][2]);
                acc[r][3] = fmaf(a.x, b0.w, acc[r][3]);
                acc[r][0] = fmaf(a.y, b1.x, acc[r][0]);
                acc[r][1] = fmaf(a.y, b1.y, acc[r][1]);
                acc[r][2] = fmaf(a.y, b1.z, acc[r][2]);
                acc[r][3] = fmaf(a.y, b1.w, acc[r][3]);
                acc[r][0] = fmaf(a.z, b2.x, acc[r][0]);
                acc[r][1] = fmaf(a.z, b2.y, acc[r][1]);
                acc[r][2] = fmaf(a.z, b2.z, acc[r][2]);
                acc[r][3] = fmaf(a.z, b2.w, acc[r][3]);
                acc[r][0] = fmaf(a.w, b3.x, acc[r][0]);
                acc[r][1] = fmaf(a.w, b3.y, acc[r][1]);
                acc[r][2] = fmaf(a.w, b3.z, acc[r][2]);
                acc[r][3] = fmaf(a.w, b3.w, acc[r][3]);
            }
        }
        __syncthreads();
    }

    float4 bb = *reinterpret_cast<const float4*>(&bias[tn]);
    #pragma unroll
    for (int r = 0; r < 4; ++r) {
        acc[r][0] += bb.x; acc[r][1] += bb.y; acc[r][2] += bb.z; acc[r][3] += bb.w;
        int gm = node0 + g + 16 * r;
        if (gm < n) {
            f32x4 hv4;
            hv4.x = acc[r][0]; hv4.y = acc[r][1]; hv4.z = acc[r][2]; hv4.w = acc[r][3];
            __builtin_nontemporal_store(hv4,
                reinterpret_cast<f32x4*>(&h[(size_t)gm * HID + tn]));
        }
    }

    const int head = v >> 2;
    const int cl = (v & 3) * 4;
    const float* arow = att + head * (2 * OUT_CH);
    float pi[4], pj[4];
    #pragma unroll
    for (int r = 0; r < 4; ++r) {
        float vi = 0.f, vj = 0.f;
        #pragma unroll
        for (int c = 0; c < 4; ++c) {
            vi = fmaf(acc[r][c], arow[cl + c], vi);
            vj = fmaf(acc[r][c], arow[OUT_CH + cl + c], vj);
        }
        pi[r] = vi + __shfl_xor(vi, 1); pi[r] += __shfl_xor(pi[r], 2);
        pj[r] = vj + __shfl_xor(vj, 1); pj[r] += __shfl_xor(pj[r], 2);
    }
    {
        int r = v & 3;
        int gm = node0 + g + 16 * r;
        if (gm < n) {
            float siv = (r == 0) ? pi[0] : (r == 1) ? pi[1] : (r == 2) ? pi[2] : pi[3];
            float sjv = (r == 0) ? pj[0] : (r == 1) ? pj[1] : (r == 2) ? pj[2] : pj[3];
            si[gm * HEADS + head] = siv;
            sj[gm * HEADS + head] = sjv;
        }
    }
}

// ---------------- fused gather + next-layer linear ----------------
// LAST=0: writes full h' row. LAST=1: writes per-head fc projections
// hp[node][head][o] (16 floats/node) -- exact push-through of the final linear.
template<int LAST>
__global__ __launch_bounds__(256) void k_gather_lin(const int* __restrict__ slots,
                        const int* __restrict__ deg,
                        const float* __restrict__ h, const float* __restrict__ si,
                        const float* __restrict__ sj,
                        const float* __restrict__ Wn, const float* __restrict__ bn,
                        const float* __restrict__ attn, const float* __restrict__ fcW,
                        float* __restrict__ h_out, float* __restrict__ si_out,
                        float* __restrict__ sj_out, int n) {
    __shared__ float Ws[HID][HID + 1];    // Ws[k][c'] = Wn[c'][k]
    __shared__ float orow[16][HID + 4];   // per-group aggregated row
    __shared__ int   sl[16][CAP];         // per-group staged slot indices

    const int tid  = threadIdx.x;
    const int lane = tid & 63;
    const int l16  = lane & 15;
    const int head = l16 >> 2;
    const int grp  = tid >> 4;
    const int node = blockIdx.x * 16 + grp;
    const bool active = node < n;

    #pragma unroll
    for (int i = 0; i < 4; ++i) {
        int f = tid + i * 256;
        int c = f >> 4;
        int k4 = (f & 15) * 4;
        float4 w = *reinterpret_cast<const float4*>(&Wn[(size_t)c * HID + k4]);
        Ws[k4 + 0][c] = w.x; Ws[k4 + 1][c] = w.y;
        Ws[k4 + 2][c] = w.z; Ws[k4 + 3][c] = w.w;
    }
    __syncthreads();

    int end = 0;
    float sid = 0.f, invd = 0.f;
    if (active) {
        int dg = deg[node];
        end = (dg < CAP ? dg : CAP);
        sid = si[node * HEADS + head];
        if (dg > 0) invd = 1.0f / (float)dg;
        int4 svv = *reinterpret_cast<const int4*>(&slots[((size_t)node << CAP_SHIFT) + l16 * 4]);
        *reinterpret_cast<int4*>(&sl[grp][l16 * 4]) = svv;
    }

    float4 acc = make_float4(0.f, 0.f, 0.f, 0.f);
    int j = 0;
    while (j < end) {
        float a[UNR];
        float4 hv[UNR];
        #pragma unroll
        for (int u = 0; u < UNR; ++u) {
            bool p = (j + u) < end;
            int idx = p ? j + u : 0;
            int s = sl[grp][idx];
            float e = sj[s * HEADS + head];
            hv[u] = *reinterpret_cast<const float4*>(&h[(size_t)s * HID + (l16 << 2)]);
            float av = sid + e;
            av = (av > 0.f) ? av : av * NEG_SLOPE;
            a[u] = p ? av : 0.f;
        }
        #pragma unroll
        for (int u = 0; u < UNR; ++u) {
            acc.x = fmaf(hv[u].x, a[u], acc.x);
            acc.y = fmaf(hv[u].y, a[u], acc.y);
            acc.z = fmaf(hv[u].z, a[u], acc.z);
            acc.w = fmaf(hv[u].w, a[u], acc.w);
        }
        j += UNR;
    }

    if (active) {
        acc.x *= invd; acc.y *= invd; acc.z *= invd; acc.w *= invd;
        *reinterpret_cast<float4*>(&orow[grp][l16 << 2]) = acc;

        const int c0 = l16 << 2;
        float4 hb = *reinterpret_cast<const float4*>(&bn[c0]);
        float h0 = hb.x, h1 = hb.y, h2 = hb.z, h3 = hb.w;
        #pragma unroll
        for (int k = 0; k < HID; ++k) {
            float o = orow[grp][k];
            float4 w = *reinterpret_cast<const float4*>(&Ws[k][c0]);
            h0 = fmaf(o, w.x, h0);
            h1 = fmaf(o, w.y, h1);
            h2 = fmaf(o, w.z, h2);
            h3 = fmaf(o, w.w, h3);
        }
        if (!LAST) {
            *reinterpret_cast<float4*>(&h_out[(size_t)node * HID + c0]) =
                make_float4(h0, h1, h2, h3);
        } else {
            float pp[OUT_SIZE];
            #pragma unroll
            for (int o = 0; o < OUT_SIZE; ++o) {
                const float* wr = fcW + o * HID + c0;
                float p = h0 * wr[0];
                p = fmaf(h1, wr[1], p);
                p = fmaf(h2, wr[2], p);
                p = fmaf(h3, wr[3], p);
                p += __shfl_xor(p, 1);
                p += __shfl_xor(p, 2);
                pp[o] = p;
            }
            int o = l16 & 3;
            float val = (o == 0) ? pp[0] : (o == 1) ? pp[1] : (o == 2) ? pp[2] : pp[3];
            h_out[(size_t)node * 16 + head * 4 + o] = val;  // hp layout [node][head][o]
        }

        const int cl = (l16 & 3) * 4;
        const float* arow = attn + head * (2 * OUT_CH);
        float hv4[4] = {h0, h1, h2, h3};
        float vi = 0.f, vj = 0.f;
        #pragma unroll
        for (int c = 0; c < 4; ++c) {
            vi = fmaf(hv4[c], arow[cl + c], vi);
            vj = fmaf(hv4[c], arow[OUT_CH + cl + c], vj);
        }
        vi += __shfl_xor(vi, 1); vi += __shfl_xor(vi, 2);
        vj += __shfl_xor(vj, 1); vj += __shfl_xor(vj, 2);
        if ((l16 & 3) == 0) {
            si_out[node * HEADS + head] = vi;
            sj_out[node * HEADS + head] = vj;
        }
    }
}

// ---------------- final gather over pre-projected hp (4B/lane/edge) ----------------
__global__ __launch_bounds__(256) void k_gather_fc2(const int* __restrict__ slots,
                        const int* __restrict__ deg,
                        const float* __restrict__ hp, const float* __restrict__ si,
                        const float* __restrict__ sj, const float* __restrict__ fcb,
                        float* __restrict__ dout, int n) {
    __shared__ int sl[16][CAP];
    const int lane = threadIdx.x & 63;
    const int l16  = lane & 15;
    const int head = l16 >> 2;
    const int grp  = threadIdx.x >> 4;
    const int node = blockIdx.x * 16 + grp;
    const bool active = node < n;

    int end = 0;
    float sid = 0.f, invd = 0.f;
    if (active) {
        int dg = deg[node];
        end = (dg < CAP ? dg : CAP);
        sid = si[node * HEADS + head];
        if (dg > 0) invd = 1.0f / (float)dg;
        int4 svv = *reinterpret_cast<const int4*>(&slots[((size_t)node << CAP_SHIFT) + l16 * 4]);
        *reinterpret_cast<int4*>(&sl[grp][l16 * 4]) = svv;
    }

    float acc = 0.f;
    int j = 0;
    while (j < end) {
        float a[UNR];
        float hv[UNR];
        #pragma unroll
        for (int u = 0; u < UNR; ++u) {
            bool p = (j + u) < end;
            int idx = p ? j + u : 0;
            int s = sl[grp][idx];
            float e = sj[s * HEADS + head];
            hv[u] = hp[(size_t)s * 16 + l16];
            float av = sid + e;
            av = (av > 0.f) ? av : av * NEG_SLOPE;
            a[u] = p ? av : 0.f;
        }
        #pragma unroll
        for (int u = 0; u < UNR; ++u) acc = fmaf(hv[u], a[u], acc);
        j += UNR;
    }
    if (active) {
        acc += __shfl_xor(acc, 4);
        acc += __shfl_xor(acc, 8);
        if (l16 < OUT_SIZE)
            dout[(size_t)node * OUT_SIZE + l16] = acc * invd + fcb[l16];
    }
}

extern "C" void kernel_launch(void* const* d_in, const int* in_sizes, int n_in,
                              void* d_out, int out_size, void* d_ws, size_t ws_size,
                              hipStream_t stream) {
    const float* x0   = (const float*)d_in[0];
    const int*   ei   = (const int*)d_in[1];
    const int E = in_sizes[1] / 2;
    const int N = in_sizes[0] / IN_CH;
    const int* srcp = ei;        // edge_index[0] = x_j (source)
    const int* dstp = ei + E;    // edge_index[1] = x_i (aggregation target)

    const float* W[4] = {(const float*)d_in[2], (const float*)d_in[5], (const float*)d_in[8],  (const float*)d_in[11]};
    const float* B[4] = {(const float*)d_in[3], (const float*)d_in[6], (const float*)d_in[9],  (const float*)d_in[12]};
    const float* A[4] = {(const float*)d_in[4], (const float*)d_in[7], (const float*)d_in[10], (const float*)d_in[13]};
    const float* fcW = (const float*)d_in[14];
    const float* fcb = (const float*)d_in[15];

    // workspace layout (ping-pong h and si/sj; slotted adjacency)
    float* ws    = (float*)d_ws;
    float* hA    = ws;                        // N*64
    float* hB    = hA  + (size_t)N * HID;     // N*64 (holds hp = N*16 for last layer)
    float* siA   = hB  + (size_t)N * HID;     // N*4
    float* sjA   = siA + (size_t)N * HEADS;   // N*4
    float* siB   = sjA + (size_t)N * HEADS;   // N*4
    float* sjB   = siB + (size_t)N * HEADS;   // N*4
    int*   cursor= (int*)(sjB + (size_t)N * HEADS);  // N (doubles as deg)
    int*   slots = cursor + N;                // N*64

    const int rng = (N + NXCD - 1) / NXCD;
    hipMemsetAsync(cursor, 0, (size_t)N * sizeof(int), stream);

    const int nchunk = (E + 2047) / 2048;
    const int nslot  = nchunk * NXCD;
    const int nlin   = (N + 63) / 64;
    const int ngroups = ((nslot + 31) / 32 > (nlin + 7) / 8) ? (nslot + 31) / 32
                                                             : (nlin + 7) / 8;
    // fused slot-fill ++ layer-0 linear (x0 -> hA, siA, sjA)
    k_prep<<<ngroups * 40, 256, 0, stream>>>(srcp, dstp, cursor, slots, E, rng, nslot,
                                             x0, W[0], B[0], A[0], hA, siA, sjA, nlin, N);

    const int gblk = (N + 15) / 16;
    // gather0 + linear1: hA -> hB
    k_gather_lin<0><<<gblk, 256, 0, stream>>>(slots, cursor, hA, siA, sjA,
                                              W[1], B[1], A[1], nullptr, hB, siB, sjB, N);
    // gather1 + linear2: hB -> hA
    k_gather_lin<0><<<gblk, 256, 0, stream>>>(slots, cursor, hB, siB, sjB,
                                              W[2], B[2], A[2], nullptr, hA, siA, sjA, N);
    // gather2 + linear3 + fc-projection: hA -> hp(=hB), si3/sj3 -> siB/sjB
    k_gather_lin<1><<<gblk, 256, 0, stream>>>(slots, cursor, hA, siA, sjA,
                                              W[3], B[3], A[3], fcW, hB, siB, sjB, N);
    // gather3 over hp + head-sum + bias: -> d_out
    k_gather_fc2<<<gblk, 256, 0, stream>>>(slots, cursor, hB, siB, sjB,
                                           fcb, (float*)d_out, N);
}

// Round 23
// 347.452 us; speedup vs baseline: 1.0197x; 1.0197x over previous
//
#include <hip/hip_runtime.h>

#define NNODES 100000
#define NEDGES 1600000
#define IN_CH 128
#define HID 64
#define HEADS 4
#define OUT_CH 16
#define OUT_SIZE 4
#define NEG_SLOPE 0.2f
#define NXCD 8
#define CAP 64
#define CAP_SHIFT 6
#define UNR 8

typedef float f32x4 __attribute__((ext_vector_type(4)));

// ---------------- fused prep: slotted edge scatter ++ layer-0 GEMM ----------------
// 40-block groups = 32 slot-fill + 8 linear blocks (complementary pipes).
// h stores are NON-TEMPORAL (bypass L2 so slot lines survive to fill).
__global__ __launch_bounds__(256, 4) void k_prep(
        const int* __restrict__ src, const int* __restrict__ dst,
        int* __restrict__ cursor, int* __restrict__ slots, int E, int rng, int nslot,
        const float* __restrict__ x, const float* __restrict__ W,
        const float* __restrict__ bias, const float* __restrict__ att,
        float* __restrict__ h, float* __restrict__ si, float* __restrict__ sj,
        int nlin, int n) {
    const int grp40 = blockIdx.x / 40;
    const int r40   = blockIdx.x % 40;

    if (r40 < 32) {
        // ---- slot-fill branch ----
        const int slotId = grp40 * 32 + r40;
        if (slotId >= nslot) return;
        const int range = slotId & (NXCD - 1);   // == blockIdx.x & 7 (physical XCD)
        const int chunk = slotId >> 3;
        const int lo = range * rng, hi = lo + rng;
        const int base = chunk * 2048 + threadIdx.x;
        #pragma unroll
        for (int i = 0; i < 8; ++i) {
            int e = base + i * 256;
            if (e < E) {
                int d = dst[e];
                if (d >= lo && d < hi) {
                    int pos = atomicAdd(&cursor[d], 1);
                    if (pos < CAP) slots[((size_t)d << CAP_SHIFT) + pos] = src[e];
                }
            }
        }
        return;
    }

    // ---- layer-0 linear branch ----
    const int linId = grp40 * 8 + (r40 - 32);
    if (linId >= nlin) return;

    constexpr int IN = IN_CH;
    constexpr int BM = 64, BK = 64;
    constexpr int LDK = BK + 16;   // 80
    constexpr int LDB = HID + 4;   // 68
    __shared__ float As[BM][LDK];
    __shared__ float Bs[BK][LDB];

    const int tid = threadIdx.x;
    const int node0 = linId * BM;
    const int g = tid >> 4;
    const int v = tid & 15;
    const int tn = v * 4;

    float acc[4][4] = {};
    float4 ra[4], rb[4];

    #pragma unroll
    for (int i = 0; i < 4; ++i) {
        int m = g + 16 * i;
        int gm = node0 + m;
        ra[i] = make_float4(0.f, 0.f, 0.f, 0.f);
        if (gm < n) ra[i] = *reinterpret_cast<const float4*>(&x[(size_t)gm * IN + tn]);
        rb[i] = *reinterpret_cast<const float4*>(&W[(size_t)m * IN + tn]);
    }

    #pragma unroll
    for (int kk = 0; kk < IN; kk += BK) {
        #pragma unroll
        for (int i = 0; i < 4; ++i) {
            int m = g + 16 * i;
            *reinterpret_cast<float4*>(&As[m][tn]) = ra[i];
            Bs[tn + 0][m] = rb[i].x; Bs[tn + 1][m] = rb[i].y;
            Bs[tn + 2][m] = rb[i].z; Bs[tn + 3][m] = rb[i].w;
        }
        __syncthreads();
        if (kk + BK < IN) {
            #pragma unroll
            for (int i = 0; i < 4; ++i) {
                int m = g + 16 * i;
                int gm = node0 + m;
                ra[i] = make_float4(0.f, 0.f, 0.f, 0.f);
                if (gm < n)
                    ra[i] = *reinterpret_cast<const float4*>(&x[(size_t)gm * IN + kk + BK + tn]);
                rb[i] = *reinterpret_cast<const float4*>(&W[(size_t)m * IN + kk + BK + tn]);
            }
        }
        #pragma unroll
        for (int k4 = 0; k4 < BK; k4 += 4) {
            float4 b0 = *reinterpret_cast<const float4*>(&Bs[k4 + 0][tn]);
            float4 b1 = *reinterpret_cast<const float4*>(&Bs[k4 + 1][tn]);
            float4 b2 = *reinterpret_cast<const float4*>(&Bs[k4 + 2][tn]);
            float4 b3 = *reinterpret_cast<const float4*>(&Bs[k4 + 3][tn]);
            #pragma unroll
            for (int r = 0; r < 4; ++r) {
                float4 a = *reinterpret_cast<const float4*>(&As[g + 16 * r][k4]);
                acc[r][0] = fmaf(a.x, b0.x, acc[r][0]);
                acc[r][1] = fmaf(a.x, b0.y, acc[r][1]);
                acc[r][2] = fmaf(a.x, b0.z, acc[r][2]);
                acc[r][3] = fmaf(a.x, b0.w, acc[r][3]);
                acc[r][0] = fmaf(a.y, b1.x, acc[r][0]);
                acc[r][1] = fmaf(a.y, b1.y, acc[r][1]);
                acc[r][2] = fmaf(a.y, b1.z, acc[r][2]);
                acc[r][3] = fmaf(a.y, b1.w, acc[r][3]);
                acc[r][0] = fmaf(a.z, b2.x, acc[r][0]);
                acc[r][1] = fmaf(a.z, b2.y, acc[r][1]);
                acc[r][2] = fmaf(a.z, b2.z, acc[r][2]);
                acc[r][3] = fmaf(a.z, b2.w, acc[r][3]);
                acc[r][0] = fmaf(a.w, b3.x, acc[r][0]);
                acc[r][1] = fmaf(a.w, b3.y, acc[r][1]);
                acc[r][2] = fmaf(a.w, b3.z, acc[r][2]);
                acc[r][3] = fmaf(a.w, b3.w, acc[r][3]);
            }
        }
        __syncthreads();
    }

    float4 bb = *reinterpret_cast<const float4*>(&bias[tn]);
    #pragma unroll
    for (int r = 0; r < 4; ++r) {
        acc[r][0] += bb.x; acc[r][1] += bb.y; acc[r][2] += bb.z; acc[r][3] += bb.w;
        int gm = node0 + g + 16 * r;
        if (gm < n) {
            f32x4 hv4;
            hv4.x = acc[r][0]; hv4.y = acc[r][1]; hv4.z = acc[r][2]; hv4.w = acc[r][3];
            __builtin_nontemporal_store(hv4,
                reinterpret_cast<f32x4*>(&h[(size_t)gm * HID + tn]));
        }
    }

    const int head = v >> 2;
    const int cl = (v & 3) * 4;
    const float* arow = att + head * (2 * OUT_CH);
    float pi[4], pj[4];
    #pragma unroll
    for (int r = 0; r < 4; ++r) {
        float vi = 0.f, vj = 0.f;
        #pragma unroll
        for (int c = 0; c < 4; ++c) {
            vi = fmaf(acc[r][c], arow[cl + c], vi);
            vj = fmaf(acc[r][c], arow[OUT_CH + cl + c], vj);
        }
        pi[r] = vi + __shfl_xor(vi, 1); pi[r] += __shfl_xor(pi[r], 2);
        pj[r] = vj + __shfl_xor(vj, 1); pj[r] += __shfl_xor(pj[r], 2);
    }
    {
        int r = v & 3;
        int gm = node0 + g + 16 * r;
        if (gm < n) {
            float siv = (r == 0) ? pi[0] : (r == 1) ? pi[1] : (r == 2) ? pi[2] : pi[3];
            float sjv = (r == 0) ? pj[0] : (r == 1) ? pj[1] : (r == 2) ? pj[2] : pj[3];
            si[gm * HEADS + head] = siv;
            sj[gm * HEADS + head] = sjv;
        }
    }
}

// ---------------- fused gather + next-layer linear ----------------
// LAST=0: writes full h' row. LAST=1: writes per-head fc projections
// hp[node][head][o] (16 floats/node) -- exact push-through of the final linear.
template<int LAST>
__global__ __launch_bounds__(256) void k_gather_lin(const int* __restrict__ slots,
                        const int* __restrict__ deg,
                        const float* __restrict__ h, const float* __restrict__ si,
                        const float* __restrict__ sj,
                        const float* __restrict__ Wn, const float* __restrict__ bn,
                        const float* __restrict__ attn, const float* __restrict__ fcW,
                        float* __restrict__ h_out, float* __restrict__ si_out,
                        float* __restrict__ sj_out, int n) {
    __shared__ float Ws[HID][HID + 1];    // Ws[k][c'] = Wn[c'][k]
    __shared__ float orow[16][HID + 4];   // per-group aggregated row
    __shared__ int   sl[16][CAP];         // per-group staged slot indices

    const int tid  = threadIdx.x;
    const int lane = tid & 63;
    const int l16  = lane & 15;
    const int head = l16 >> 2;
    const int grp  = tid >> 4;
    const int node = blockIdx.x * 16 + grp;
    const bool active = node < n;

    #pragma unroll
    for (int i = 0; i < 4; ++i) {
        int f = tid + i * 256;
        int c = f >> 4;
        int k4 = (f & 15) * 4;
        float4 w = *reinterpret_cast<const float4*>(&Wn[(size_t)c * HID + k4]);
        Ws[k4 + 0][c] = w.x; Ws[k4 + 1][c] = w.y;
        Ws[k4 + 2][c] = w.z; Ws[k4 + 3][c] = w.w;
    }
    __syncthreads();

    int end = 0;
    float sid = 0.f, invd = 0.f;
    if (active) {
        int dg = deg[node];
        end = (dg < CAP ? dg : CAP);
        sid = si[node * HEADS + head];
        if (dg > 0) invd = 1.0f / (float)dg;
        int4 svv = *reinterpret_cast<const int4*>(&slots[((size_t)node << CAP_SHIFT) + l16 * 4]);
        *reinterpret_cast<int4*>(&sl[grp][l16 * 4]) = svv;
    }

    float4 acc = make_float4(0.f, 0.f, 0.f, 0.f);
    int j = 0;
    while (j < end) {
        float a[UNR];
        float4 hv[UNR];
        #pragma unroll
        for (int u = 0; u < UNR; ++u) {
            bool p = (j + u) < end;
            int idx = p ? j + u : 0;
            int s = sl[grp][idx];
            float e = sj[s * HEADS + head];
            hv[u] = *reinterpret_cast<const float4*>(&h[(size_t)s * HID + (l16 << 2)]);
            float av = sid + e;
            av = (av > 0.f) ? av : av * NEG_SLOPE;
            a[u] = p ? av : 0.f;
        }
        #pragma unroll
        for (int u = 0; u < UNR; ++u) {
            acc.x = fmaf(hv[u].x, a[u], acc.x);
            acc.y = fmaf(hv[u].y, a[u], acc.y);
            acc.z = fmaf(hv[u].z, a[u], acc.z);
            acc.w = fmaf(hv[u].w, a[u], acc.w);
        }
        j += UNR;
    }

    if (active) {
        acc.x *= invd; acc.y *= invd; acc.z *= invd; acc.w *= invd;
        *reinterpret_cast<float4*>(&orow[grp][l16 << 2]) = acc;

        const int c0 = l16 << 2;
        float4 hb = *reinterpret_cast<const float4*>(&bn[c0]);
        float h0 = hb.x, h1 = hb.y, h2 = hb.z, h3 = hb.w;
        #pragma unroll
        for (int k = 0; k < HID; ++k) {
            float o = orow[grp][k];
            float4 w = *reinterpret_cast<const float4*>(&Ws[k][c0]);
            h0 = fmaf(o, w.x, h0);
            h1 = fmaf(o, w.y, h1);
            h2 = fmaf(o, w.z, h2);
            h3 = fmaf(o, w.w, h3);
        }
        if (!LAST) {
            *reinterpret_cast<float4*>(&h_out[(size_t)node * HID + c0]) =
                make_float4(h0, h1, h2, h3);
        } else {
            float pp[OUT_SIZE];
            #pragma unroll
            for (int o = 0; o < OUT_SIZE; ++o) {
                const float* wr = fcW + o * HID + c0;
                float p = h0 * wr[0];
                p = fmaf(h1, wr[1], p);
                p = fmaf(h2, wr[2], p);
                p = fmaf(h3, wr[3], p);
                p += __shfl_xor(p, 1);
                p += __shfl_xor(p, 2);
                pp[o] = p;
            }
            int o = l16 & 3;
            float val = (o == 0) ? pp[0] : (o == 1) ? pp[1] : (o == 2) ? pp[2] : pp[3];
            h_out[(size_t)node * 16 + head * 4 + o] = val;  // hp layout [node][head][o]
        }

        const int cl = (l16 & 3) * 4;
        const float* arow = attn + head * (2 * OUT_CH);
        float hv4[4] = {h0, h1, h2, h3};
        float vi = 0.f, vj = 0.f;
        #pragma unroll
        for (int c = 0; c < 4; ++c) {
            vi = fmaf(hv4[c], arow[cl + c], vi);
            vj = fmaf(hv4[c], arow[OUT_CH + cl + c], vj);
        }
        vi += __shfl_xor(vi, 1); vi += __shfl_xor(vi, 2);
        vj += __shfl_xor(vj, 1); vj += __shfl_xor(vj, 2);
        if ((l16 & 3) == 0) {
            si_out[node * HEADS + head] = vi;
            sj_out[node * HEADS + head] = vj;
        }
    }
}

// ---------------- final gather over pre-projected hp (4B/lane/edge) ----------------
__global__ __launch_bounds__(256) void k_gather_fc2(const int* __restrict__ slots,
                        const int* __restrict__ deg,
                        const float* __restrict__ hp, const float* __restrict__ si,
                        const float* __restrict__ sj, const float* __restrict__ fcb,
                        float* __restrict__ dout, int n) {
    __shared__ int sl[16][CAP];
    const int lane = threadIdx.x & 63;
    const int l16  = lane & 15;
    const int head = l16 >> 2;
    const int grp  = threadIdx.x >> 4;
    const int node = blockIdx.x * 16 + grp;
    const bool active = node < n;

    int end = 0;
    float sid = 0.f, invd = 0.f;
    if (active) {
        int dg = deg[node];
        end = (dg < CAP ? dg : CAP);
        sid = si[node * HEADS + head];
        if (dg > 0) invd = 1.0f / (float)dg;
        int4 svv = *reinterpret_cast<const int4*>(&slots[((size_t)node << CAP_SHIFT) + l16 * 4]);
        *reinterpret_cast<int4*>(&sl[grp][l16 * 4]) = svv;
    }

    float acc = 0.f;
    int j = 0;
    while (j < end) {
        float a[UNR];
        float hv[UNR];
        #pragma unroll
        for (int u = 0; u < UNR; ++u) {
            bool p = (j + u) < end;
            int idx = p ? j + u : 0;
            int s = sl[grp][idx];
            float e = sj[s * HEADS + head];
            hv[u] = hp[(size_t)s * 16 + l16];
            float av = sid + e;
            av = (av > 0.f) ? av : av * NEG_SLOPE;
            a[u] = p ? av : 0.f;
        }
        #pragma unroll
        for (int u = 0; u < UNR; ++u) acc = fmaf(hv[u], a[u], acc);
        j += UNR;
    }
    if (active) {
        acc += __shfl_xor(acc, 4);
        acc += __shfl_xor(acc, 8);
        if (l16 < OUT_SIZE)
            dout[(size_t)node * OUT_SIZE + l16] = acc * invd + fcb[l16];
    }
}

extern "C" void kernel_launch(void* const* d_in, const int* in_sizes, int n_in,
                              void* d_out, int out_size, void* d_ws, size_t ws_size,
                              hipStream_t stream) {
    const float* x0   = (const float*)d_in[0];
    const int*   ei   = (const int*)d_in[1];
    const int E = in_sizes[1] / 2;
    const int N = in_sizes[0] / IN_CH;
    const int* srcp = ei;        // edge_index[0] = x_j (source)
    const int* dstp = ei + E;    // edge_index[1] = x_i (aggregation target)

    const float* W[4] = {(const float*)d_in[2], (const float*)d_in[5], (const float*)d_in[8],  (const float*)d_in[11]};
    const float* B[4] = {(const float*)d_in[3], (const float*)d_in[6], (const float*)d_in[9],  (const float*)d_in[12]};
    const float* A[4] = {(const float*)d_in[4], (const float*)d_in[7], (const float*)d_in[10], (const float*)d_in[13]};
    const float* fcW = (const float*)d_in[14];
    const float* fcb = (const float*)d_in[15];

    // workspace layout (ping-pong h and si/sj; slotted adjacency)
    float* ws    = (float*)d_ws;
    float* hA    = ws;                        // N*64
    float* hB    = hA  + (size_t)N * HID;     // N*64 (holds hp = N*16 for last layer)
    float* siA   = hB  + (size_t)N * HID;     // N*4
    float* sjA   = siA + (size_t)N * HEADS;   // N*4
    float* siB   = sjA + (size_t)N * HEADS;   // N*4
    float* sjB   = siB + (size_t)N * HEADS;   // N*4
    int*   cursor= (int*)(sjB + (size_t)N * HEADS);  // N (doubles as deg)
    int*   slots = cursor + N;                // N*64

    const int rng = (N + NXCD - 1) / NXCD;
    hipMemsetAsync(cursor, 0, (size_t)N * sizeof(int), stream);

    const int nchunk = (E + 2047) / 2048;
    const int nslot  = nchunk * NXCD;
    const int nlin   = (N + 63) / 64;
    const int ngroups = ((nslot + 31) / 32 > (nlin + 7) / 8) ? (nslot + 31) / 32
                                                             : (nlin + 7) / 8;
    // fused slot-fill ++ layer-0 linear (x0 -> hA, siA, sjA)
    k_prep<<<ngroups * 40, 256, 0, stream>>>(srcp, dstp, cursor, slots, E, rng, nslot,
                                             x0, W[0], B[0], A[0], hA, siA, sjA, nlin, N);

    const int gblk = (N + 15) / 16;
    // gather0 + linear1: hA -> hB
    k_gather_lin<0><<<gblk, 256, 0, stream>>>(slots, cursor, hA, siA, sjA,
                                              W[1], B[1], A[1], nullptr, hB, siB, sjB, N);
    // gather1 + linear2: hB -> hA
    k_gather_lin<0><<<gblk, 256, 0, stream>>>(slots, cursor, hB, siB, sjB,
                                              W[2], B[2], A[2], nullptr, hA, siA, sjA, N);
    // gather2 + linear3 + fc-projection: hA -> hp(=hB), si3/sj3 -> siB/sjB
    k_gather_lin<1><<<gblk, 256, 0, stream>>>(slots, cursor, hA, siA, sjA,
                                              W[3], B[3], A[3], fcW, hB, siB, sjB, N);
    // gather3 over hp + head-sum + bias: -> d_out
    k_gather_fc2<<<gblk, 256, 0, stream>>>(slots, cursor, hB, siB, sjB,
                                           fcb, (float*)d_out, N);
}